// Round 8
// baseline (1090.134 us; speedup 1.0000x reference)
//
#include <hip/hip_runtime.h>
#include <hip/hip_bf16.h>
#include <math.h>

#define VOCAB 50257
#define NCLS 20
#define EDIM 64
#define HDIM 64
#define BATCH 128
#define TLEN 2048

typedef float v2f __attribute__((ext_vector_type(2)));

// Static device scratch: no dependence on ws_size, graph-capture safe.
__device__ float g_P[(size_t)2 * VOCAB * 192];   // 77.2 MB, input-projected vocab table (bias folded)
__device__ float g_feats[BATCH * 256];           // pooled features

__device__ __forceinline__ float fast_rcp(float x) { return __builtin_amdgcn_rcpf(x); }

__device__ __forceinline__ float fsigmoid(float x) {
    return fast_rcp(1.f + __expf(-x));
}
__device__ __forceinline__ float ftanh(float x) {
    float e = __expf(2.f * x);
    return 1.f - 2.f * fast_rcp(e + 1.f);
}

// ---------------- Kernel A: P[dir][v][g] = dot(emb[v], wih[dir][g]) + bih[dir][g] ----------------
__global__ __launch_bounds__(384) void precompute_P(
    const float* __restrict__ emb,
    const float* __restrict__ wih_f, const float* __restrict__ bih_f,
    const float* __restrict__ wih_b, const float* __restrict__ bih_b)
{
    const int t = threadIdx.x;
    const int dir = t / 192;
    const int g = t % 192;
    const float* wih = dir ? wih_b : wih_f;
    const float* bih = dir ? bih_b : bih_f;

    float4 wq0, wq1, wq2, wq3, wq4, wq5, wq6, wq7;
    float4 wq8, wq9, wq10, wq11, wq12, wq13, wq14, wq15;
#define LDWQ(K) wq##K = *(const float4*)(wih + (size_t)g * 64 + 4 * K)
    LDWQ(0); LDWQ(1); LDWQ(2); LDWQ(3); LDWQ(4); LDWQ(5); LDWQ(6); LDWQ(7);
    LDWQ(8); LDWQ(9); LDWQ(10); LDWQ(11); LDWQ(12); LDWQ(13); LDWQ(14); LDWQ(15);
#undef LDWQ
    const float bias = bih[g];
    float* Pd = g_P + (size_t)dir * VOCAB * 192;

    for (int v = blockIdx.x * 2; v < VOCAB; v += gridDim.x * 2) {
        const int v1ok = (v + 1 < VOCAB);
        const float4* e0 = (const float4*)(emb + (size_t)v * 64);
        const float4* e1 = (const float4*)(emb + (size_t)(v1ok ? v + 1 : v) * 64);
        float a0 = bias, a1 = bias;
#define PFMA(K) do {                                   \
            float4 x = e0[K];                          \
            float4 y = e1[K];                          \
            a0 = fmaf(x.x, wq##K.x, a0);               \
            a1 = fmaf(y.x, wq##K.x, a1);               \
            a0 = fmaf(x.y, wq##K.y, a0);               \
            a1 = fmaf(y.y, wq##K.y, a1);               \
            a0 = fmaf(x.z, wq##K.z, a0);               \
            a1 = fmaf(y.z, wq##K.z, a1);               \
            a0 = fmaf(x.w, wq##K.w, a0);               \
            a1 = fmaf(y.w, wq##K.w, a1);               \
        } while (0)
        PFMA(0); PFMA(1); PFMA(2); PFMA(3); PFMA(4); PFMA(5); PFMA(6); PFMA(7);
        PFMA(8); PFMA(9); PFMA(10); PFMA(11); PFMA(12); PFMA(13); PFMA(14); PFMA(15);
#undef PFMA
        Pd[(size_t)v * 192 + g] = a0;
        if (v1ok) Pd[(size_t)(v + 1) * 192 + g] = a1;
    }
}

// ---------------- Kernel B: 12 waves, ONE barrier/step, parallel-redundant combine ----------------
// Post-R7 diagnosis: spills never mattered (R4 heavy-spill == R7 spill-free == ~1030 cyc/step).
// The chain is {h-read RT + dot + sigmoid + drain + barrier} + {WAVE2-ONLY r/z read RT + tanh +
// h write + drain + barrier}. This version removes the second barrier and the phase-2
// serialization entirely:
//  phase-1: quad-split dots (R7 layout, proven 40-VGPR allocation); c==0 lanes write r/z/hnb
//           (hnb = n-dot + bn) into PARITY-DOUBLE-BUFFERED LDS arrays.
//  ONE barrier. Then EVERY lane of EVERY wave redundantly computes n,h for unit l=lane&63
//  (r/z/hnb[l] from LDS, xn[l] from its own ring) and writes h_lds[l]: each wave writes the
//  FULL h vector with bit-identical values, so the next step's h-read is ordered in-wave and
//  needs NO barrier. Double-buffering makes the 1-barrier scheme race-free: the set-A writer
//  at step s+2 runs after barrier(s+1), whose release requires set-A readers of step s to
//  have consumed their reads (h-write data dependency forces retirement before arrival).
// Ring: uniform 2 asm loads/step/lane (xg for phase-1 u, xn for phase-2 l), depth 4,
// tied s_waitcnt vmcnt(6) (8 in flight, retire oldest pair). No sched_barrier walls.
__global__ __launch_bounds__(768, 1) void gru_seq(
    const int* __restrict__ tokens,
    const float* __restrict__ whh_f, const float* __restrict__ bhh_f,
    const float* __restrict__ whh_b, const float* __restrict__ bhh_b)
{
    const int tid = threadIdx.x;
    const int gate = tid >> 8;           // 0=r, 1=z, 2=n (4 whole waves per gate)
    const int j = tid & 255;
    const int u = j >> 2;                // phase-1 output unit 0..63
    const int c = j & 3;                 // phase-1 K-chunk 0..3
    const int lane = tid & 63;           // phase-2 output unit (per-wave full coverage)
    const int blk = blockIdx.x;
    const int b = blk >> 1;
    const int dir = blk & 1;
    const float* whh = dir ? whh_b : whh_f;
    const float* bhh = dir ? bhh_b : bhh_f;
    const float* Pbase = g_P + (size_t)dir * VOCAB * 192;
    const float* Pg = Pbase + gate * 64 + u;     // phase-1 gate value for unit u
    const float* Pn = Pbase + 128 + lane;        // phase-2 xn for unit lane

    __shared__ __align__(16) float h_lds[64];
    __shared__ float r_lds[2][64];
    __shared__ float z_lds[2][64];
    __shared__ float hnb_lds[2][64];
    __shared__ __align__(16) int tok_lds[TLEN];

    {
        const int4* src = (const int4*)(tokens + (size_t)b * TLEN);
        int4* dst = (int4*)tok_lds;
        for (int t = tid; t < TLEN / 4; t += 768) dst[t] = src[t];
    }

    // phase-1 weights: 16 floats -> 8 named v2f (proven register-resident at this shape)
    v2f w0, w1, w2, w3, w4, w5, w6, w7;
    {
        const float4* p = (const float4*)(whh + (size_t)(gate * 64 + u) * 64 + c * 16);
        float4 q0 = p[0]; w0 = (v2f){q0.x, q0.y}; w1 = (v2f){q0.z, q0.w};
        float4 q1 = p[1]; w2 = (v2f){q1.x, q1.y}; w3 = (v2f){q1.z, q1.w};
        float4 q2 = p[2]; w4 = (v2f){q2.x, q2.y}; w5 = (v2f){q2.z, q2.w};
        float4 q3 = p[3]; w6 = (v2f){q3.x, q3.y}; w7 = (v2f){q3.z, q3.w};
    }
    const float bias = bhh[gate * 64 + u];       // phase-1 bias (br/bz/bn for unit u)

    if (tid < 64) h_lds[tid] = 0.f;
    float h = 0.f, sum = 0.f, mx = -INFINITY;    // phase-2 state for unit `lane` (per wave)
    __syncthreads();    // prologue only: tok_lds + h_lds visible (ring not yet started)

    auto tok_at = [&](int s) -> int {
        int ss = s < TLEN ? s : TLEN - 1;        // clamp for tail prefetches (values unused)
        return tok_lds[dir ? (TLEN - 1 - ss) : ss];
    };

    // depth-4 ring, 2 loads per slot: xg (phase-1), xn (phase-2); order fixed by volatile asm
    float xg0, xg1, xg2, xg3, xn0, xn1, xn2, xn3;
#define GRU_PRE(SL, D) do {                                                        \
        const size_t o_ = (size_t)tok_at(D) * 192;                                 \
        asm volatile("global_load_dword %0, %1, off" : "=v"(xg##SL) : "v"(Pg + o_)); \
        asm volatile("global_load_dword %0, %1, off" : "=v"(xn##SL) : "v"(Pn + o_)); \
    } while (0)
    GRU_PRE(0, 0); GRU_PRE(1, 1); GRU_PRE(2, 2); GRU_PRE(3, 3);

#define GRU_STEP(SL, SB, PAR) do {                                                 \
        const int tN_ = tok_at((SB) + 4);                                          \
        /* phase 1: quad-split dot over h_lds (identical f32 order to round 7) */  \
        const float4* hb_ = (const float4*)(h_lds + c * 16);                       \
        v2f a0 = {0.f, 0.f}, a1 = {0.f, 0.f};                                      \
        { float4 h4_ = hb_[0];                                                     \
          a0 = __builtin_elementwise_fma((v2f){h4_.x, h4_.y}, w0, a0);             \
          a1 = __builtin_elementwise_fma((v2f){h4_.z, h4_.w}, w1, a1); }           \
        { float4 h4_ = hb_[1];                                                     \
          a0 = __builtin_elementwise_fma((v2f){h4_.x, h4_.y}, w2, a0);             \
          a1 = __builtin_elementwise_fma((v2f){h4_.z, h4_.w}, w3, a1); }           \
        { float4 h4_ = hb_[2];                                                     \
          a0 = __builtin_elementwise_fma((v2f){h4_.x, h4_.y}, w4, a0);             \
          a1 = __builtin_elementwise_fma((v2f){h4_.z, h4_.w}, w5, a1); }           \
        { float4 h4_ = hb_[3];                                                     \
          a0 = __builtin_elementwise_fma((v2f){h4_.x, h4_.y}, w6, a0);             \
          a1 = __builtin_elementwise_fma((v2f){h4_.z, h4_.w}, w7, a1); }           \
        float p_ = (a0.x + a0.y) + (a1.x + a1.y);                                  \
        float t_ = p_ + __shfl_xor(p_, 1);                                         \
        float hg = t_ + __shfl_xor(t_, 2);                                         \
        /* retire oldest ring pair; both slot regs tied (uses cannot hoist) */     \
        asm volatile("s_waitcnt vmcnt(6)" : "+v"(xg##SL), "+v"(xn##SL));           \
        if (gate == 2) {                                                           \
            if (c == 0) hnb_lds[PAR][u] = hg + bias;                               \
        } else {                                                                   \
            float g_ = fsigmoid(xg##SL + hg + bias);                               \
            if (c == 0) { float* d_ = (gate == 0) ? r_lds[PAR] : z_lds[PAR];       \
                          d_[u] = g_; }                                            \
        }                                                                          \
        asm volatile("s_waitcnt lgkmcnt(0)" ::: "memory");                         \
        __builtin_amdgcn_s_barrier();          /* ONE barrier per step */          \
        asm volatile("" ::: "memory");                                             \
        /* phase 2: every wave computes the FULL h vector redundantly */           \
        {                                                                          \
            float r_ = r_lds[PAR][lane];                                           \
            float z_ = z_lds[PAR][lane];                                           \
            float hnb_ = hnb_lds[PAR][lane];                                       \
            float n_ = ftanh(xn##SL + r_ * hnb_);                                  \
            h = fmaf(z_, h - n_, n_);          /* (1-z)*n + z*h */                 \
            sum += h;                                                              \
            mx = fmaxf(mx, h);                                                     \
            h_lds[lane] = h;   /* 12 waves write identical bits: benign */         \
        }                                                                          \
        /* refill slot (addresses known 4 steps ahead) */                          \
        const size_t o_ = (size_t)tN_ * 192;                                       \
        asm volatile("global_load_dword %0, %1, off" : "=v"(xg##SL) : "v"(Pg + o_)); \
        asm volatile("global_load_dword %0, %1, off" : "=v"(xn##SL) : "v"(Pn + o_)); \
    } while (0)

    for (int s = 0; s < TLEN; s += 4) {
        GRU_STEP(0, s + 0, 0);
        GRU_STEP(1, s + 1, 1);
        GRU_STEP(2, s + 2, 0);
        GRU_STEP(3, s + 3, 1);
    }
    asm volatile("s_waitcnt vmcnt(0)" ::: "memory");   // drain tail prefetches

    // feats layout [b][256]: [mean_f | mean_b | max_f | max_b]; wave 0 has full state
    if (tid < 64) {
        g_feats[b * 256 + dir * 64 + lane] = sum * (1.f / TLEN);
        g_feats[b * 256 + 128 + dir * 64 + lane] = mx;
    }
#undef GRU_PRE
#undef GRU_STEP
}

// ---------------- Kernel C: classifier  out = W2 @ gelu(W1 @ feats + b1) + b2 ----------------
__global__ __launch_bounds__(64) void classifier(
    const float* __restrict__ w1, const float* __restrict__ b1,
    const float* __restrict__ w2, const float* __restrict__ b2,
    float* __restrict__ out)
{
    const int b = blockIdx.x;
    const int i = threadIdx.x;
    __shared__ float f[256];
    __shared__ float hid[64];
    for (int c = i; c < 256; c += 64) f[c] = g_feats[b * 256 + c];
    __syncthreads();

    float acc = b1[i];
    const float* wrow = w1 + (size_t)i * 256;
#pragma unroll 16
    for (int c = 0; c < 256; c++) acc = fmaf(f[c], wrow[c], acc);
    hid[i] = acc * 0.5f * (1.f + erff(acc * 0.70710678118654752f));
    __syncthreads();

    if (i < NCLS) {
        float o = b2[i];
        const float* w2r = w2 + (size_t)i * 64;
#pragma unroll
        for (int j = 0; j < 64; j++) o = fmaf(hid[j], w2r[j], o);
        out[b * NCLS + i] = o;
    }
}

extern "C" void kernel_launch(void* const* d_in, const int* in_sizes, int n_in,
                              void* d_out, int out_size, void* d_ws, size_t ws_size,
                              hipStream_t stream) {
    const int*   tokens = (const int*)  d_in[0];
    const float* emb    = (const float*)d_in[1];
    const float* wih_f  = (const float*)d_in[2];
    const float* whh_f  = (const float*)d_in[3];
    const float* bih_f  = (const float*)d_in[4];
    const float* bhh_f  = (const float*)d_in[5];
    const float* wih_b  = (const float*)d_in[6];
    const float* whh_b  = (const float*)d_in[7];
    const float* bih_b  = (const float*)d_in[8];
    const float* bhh_b  = (const float*)d_in[9];
    const float* w1     = (const float*)d_in[10];
    const float* b1     = (const float*)d_in[11];
    const float* w2     = (const float*)d_in[12];
    const float* b2     = (const float*)d_in[13];
    float* out = (float*)d_out;

    precompute_P<<<4096, 384, 0, stream>>>(emb, wih_f, bih_f, wih_b, bih_b);
    gru_seq<<<2 * BATCH, 768, 0, stream>>>(tokens, whh_f, bhh_f, whh_b, bhh_b);
    classifier<<<BATCH, 64, 0, stream>>>(w1, b1, w2, b2, out);
}